// Round 8
// baseline (342.261 us; speedup 1.0000x reference)
//
#include <hip/hip_runtime.h>
#include <hip/hip_bf16.h>
#include <math.h>

#define B_ 32
#define H_ 1024
#define S_ 1024

typedef float  f32x4_t  __attribute__((ext_vector_type(4)));
typedef float  f32x16_t __attribute__((ext_vector_type(16)));
typedef long long i64;
typedef i64 i64x2 __attribute__((ext_vector_type(2)));
typedef unsigned char u8;

// async global->LDS, 16B per lane; LDS dest = wave-uniform base + lane*16.
__device__ __forceinline__ void gl_lds16(const void* g, void* l) {
    __builtin_amdgcn_global_load_lds(
        (const __attribute__((address_space(1))) unsigned int*)g,
        (__attribute__((address_space(3))) unsigned int*)l, 16, 0, 0);
}

// tanh via hw exp2 + rcp (~5 VALU inst, ~1e-6 abs err; saturates correctly)
__device__ __forceinline__ float tanh_fast(float x) {
    float e = __builtin_amdgcn_exp2f(x * 2.885390081777927f);  // e^(2x)
    return 1.f - 2.f * __builtin_amdgcn_rcpf(e + 1.f);
}

// fp8 k-permutation within a 32-k group: swap bits 3<->4 (involution).
__device__ __forceinline__ int kperm(int k) {
    return (k & ~24) | ((k & 8) << 1) | ((k & 16) >> 1);
}

// ---------------------------------------------------------------------------
// prep (one dispatch, 3 roles):
//  [0,1024):     encF8[b][kt][s][32B] = e4m3(enc[b][k][s]). Thread = (b,kt,
//                4 consecutive s): 32 float4 loads (wave reads contiguous
//                1KB segments, 32-deep ILP), register pack, 16B stores.
//  [1024,2048):  W2f8[kt][h][32B] = e4m3(64 * W[h][H+k]) + zero logits/ctx
//  [2048,2304):  t1[b,h] = bias[h] + sum_k hidden[b,k]*W[h,k]  (wave per h)
// ---------------------------------------------------------------------------
__global__ __launch_bounds__(256) void prep_kernel(
    const float* __restrict__ enc, const float* __restrict__ W,
    const float* __restrict__ hidden, const float* __restrict__ bias,
    u8* __restrict__ encF8, u8* __restrict__ W2f8,
    float* __restrict__ t1, float* __restrict__ logits,
    float* __restrict__ ctx)
{
    const int idx = blockIdx.x;
    const int tid = threadIdx.x;
    if (idx < 1024) {
        const int b  = idx >> 5;
        const int kt = idx & 31;
        const int s  = tid * 4;
        const float* ebase = enc + ((size_t)b * S_ + kt * 32) * H_ + s;
        f32x4_t L[32];
        #pragma unroll
        for (int kk = 0; kk < 32; ++kk)
            L[kk] = *reinterpret_cast<const f32x4_t*>(ebase + (size_t)kk * H_);
        u8* obase = encF8 + (size_t)b * 1048576 + (size_t)kt * 32768 + (size_t)s * 32;
        #pragma unroll
        for (int jj = 0; jj < 4; ++jj)
            #pragma unroll
            for (int c2 = 0; c2 < 2; ++c2) {
                int w4[4];
                #pragma unroll
                for (int w = 0; w < 4; ++w) {
                    int i0 = 4 * w;
                    float f0 = L[16 * ((i0 + 0) >> 3) + 8 * c2 + ((i0 + 0) & 7)][jj];
                    float f1 = L[16 * ((i0 + 1) >> 3) + 8 * c2 + ((i0 + 1) & 7)][jj];
                    float f2 = L[16 * ((i0 + 2) >> 3) + 8 * c2 + ((i0 + 2) & 7)][jj];
                    float f3 = L[16 * ((i0 + 3) >> 3) + 8 * c2 + ((i0 + 3) & 7)][jj];
                    int pw = __builtin_amdgcn_cvt_pk_fp8_f32(f0, f1, 0, false);
                    pw     = __builtin_amdgcn_cvt_pk_fp8_f32(f2, f3, pw, true);
                    w4[w] = pw;
                }
                int4 payload = { w4[0], w4[1], w4[2], w4[3] };
                *reinterpret_cast<int4*>(obase + jj * 32 + c2 * 16) = payload;
            }
    } else if (idx < 2048) {
        int h = idx - 1024;  // one h row
        if (tid < 64) {      // zero logits (first 32768) then ctx (next 32768)
            int z = h * 64 + tid;
            if (z < B_ * S_) logits[z] = 0.f;
            else             ctx[z - B_ * S_] = 0.f;
        }
        int kt = tid >> 3;            // 0..31
        int q  = tid & 7;             // dest 4-byte word in 32B chunk
        int src = kperm(q * 4);       // contiguous 4 source floats
        float4 wv = *reinterpret_cast<const float4*>(
            W + (size_t)h * (2 * H_) + H_ + kt * 32 + src);
        int pw = __builtin_amdgcn_cvt_pk_fp8_f32(wv.x * 64.f, wv.y * 64.f, 0, false);
        pw     = __builtin_amdgcn_cvt_pk_fp8_f32(wv.z * 64.f, wv.w * 64.f, pw, true);
        *reinterpret_cast<int*>(W2f8 + (size_t)kt * 32768 + (size_t)h * 32 + q * 4) = pw;
    } else {
        int h    = (idx - 2048) * 4 + (tid >> 6);
        int lane = tid & 63;
        const float4* wp = reinterpret_cast<const float4*>(W + (size_t)h * (2 * H_));
        float4 w0 = wp[lane], w1 = wp[lane + 64], w2 = wp[lane + 128], w3 = wp[lane + 192];
        float bh = bias[h];
        for (int b = 0; b < B_; ++b) {
            const float4* hp = reinterpret_cast<const float4*>(hidden + b * H_);
            float4 h0 = hp[lane], h1 = hp[lane + 64], h2 = hp[lane + 128], h3 = hp[lane + 192];
            float a = w0.x*h0.x + w0.y*h0.y + w0.z*h0.z + w0.w*h0.w
                    + w1.x*h1.x + w1.y*h1.y + w1.z*h1.z + w1.w*h1.w
                    + w2.x*h2.x + w2.y*h2.y + w2.z*h2.z + w2.w*h2.w
                    + w3.x*h3.x + w3.y*h3.y + w3.z*h3.z + w3.w*h3.w;
            #pragma unroll
            for (int off = 1; off < 64; off <<= 1) a += __shfl_xor(a, off);
            if (lane == 0) t1[b * H_ + h] = a + bh;
        }
    }
}

// ---------------------------------------------------------------------------
// Energy GEMM (round-6 config, measured 78 µs / MfmaUtil 35% / FETCH 21 MB):
// fp8 e4m3, 128x128 tile, 32x32x16 MFMA (2x2/wave), BK=64 barrier segments,
// double-buffered (32 KB LDS). XCD swizzle: all 8 h-tiles of one (s,b) group
// share id%8 -> same XCD -> B s-tile L2-resident. Zero-conflict slot map
// (verified SQ_LDS_BANK_CONFLICT=0 rounds 4-6).
//   D[h,s] = sum_k W2[h,k]*enc[b,k,s]; logits[b,s] += sum_h v[h]*tanh(D+t1)
// ---------------------------------------------------------------------------
__global__ __launch_bounds__(256) void energy_kernel(
    const u8* __restrict__ W2f8, const u8* __restrict__ encF8,
    const float* __restrict__ t1, const float* __restrict__ v,
    float* __restrict__ logits)
{
    __shared__ __align__(16) u8 As[2][2][4096];
    __shared__ __align__(16) u8 Bs[2][2][4096];

    const int id = blockIdx.x;
    const int q  = id >> 3, r = id & 7;
    const int ht = q & 7;
    const int g  = r + ((q >> 3) << 3);
    const int b  = g >> 3;
    const int h0 = ht * 128;
    const int s0 = (g & 7) * 128;

    const int tid   = threadIdx.x;
    const int lane  = tid & 63;
    const int wid   = tid >> 6;
    const int wm    = (wid & 1) * 64;
    const int wn    = (wid >> 1) * 64;
    const int l32   = lane & 31;
    const int khalf = lane >> 5;

    const int rowl = ((lane & 3) << 3) | ((lane >> 2) & 7);
    const int row  = (wid << 5) | rowl;
    const int cch  = lane >> 5;
    const size_t gofsA = (size_t)(h0 + row) * 32 + cch * 16;
    const size_t gofsB = (size_t)b * 1048576 + (size_t)(s0 + row) * 32 + cch * 16;

    gl_lds16(W2f8 + gofsA,          &As[0][0][tid * 16]);
    gl_lds16(W2f8 + gofsA + 32768,  &As[0][1][tid * 16]);
    gl_lds16(encF8 + gofsB,         &Bs[0][0][tid * 16]);
    gl_lds16(encF8 + gofsB + 32768, &Bs[0][1][tid * 16]);
    __syncthreads();

    f32x16_t acc[2][2] = {};
    const int sl  = ((((l32 & 7) << 2) | (l32 >> 3)) | (khalf << 5)) * 16;
    const int wAo = (wm >> 5) * 1024;
    const int wBo = (wn >> 5) * 1024;

    for (int seg = 0; seg < 16; ++seg) {
        const int cur = seg & 1, nxt = cur ^ 1;
        if (seg < 15) {
            const size_t o = (size_t)(2 * seg + 2) * 32768;
            gl_lds16(W2f8 + gofsA + o,          &As[nxt][0][tid * 16]);
            gl_lds16(W2f8 + gofsA + o + 32768,  &As[nxt][1][tid * 16]);
            gl_lds16(encF8 + gofsB + o,         &Bs[nxt][0][tid * 16]);
            gl_lds16(encF8 + gofsB + o + 32768, &Bs[nxt][1][tid * 16]);
        }
        #pragma unroll
        for (int t = 0; t < 2; ++t) {
            i64x2 a0 = *reinterpret_cast<const i64x2*>(&As[cur][t][wAo + sl]);
            i64x2 a1 = *reinterpret_cast<const i64x2*>(&As[cur][t][wAo + 1024 + sl]);
            i64x2 b0 = *reinterpret_cast<const i64x2*>(&Bs[cur][t][wBo + sl]);
            i64x2 b1 = *reinterpret_cast<const i64x2*>(&Bs[cur][t][wBo + 1024 + sl]);
            acc[0][0] = __builtin_amdgcn_mfma_f32_32x32x16_fp8_fp8(a0.x, b0.x, acc[0][0], 0, 0, 0);
            acc[0][1] = __builtin_amdgcn_mfma_f32_32x32x16_fp8_fp8(a0.x, b1.x, acc[0][1], 0, 0, 0);
            acc[1][0] = __builtin_amdgcn_mfma_f32_32x32x16_fp8_fp8(a1.x, b0.x, acc[1][0], 0, 0, 0);
            acc[1][1] = __builtin_amdgcn_mfma_f32_32x32x16_fp8_fp8(a1.x, b1.x, acc[1][1], 0, 0, 0);
            acc[0][0] = __builtin_amdgcn_mfma_f32_32x32x16_fp8_fp8(a0.y, b0.y, acc[0][0], 0, 0, 0);
            acc[0][1] = __builtin_amdgcn_mfma_f32_32x32x16_fp8_fp8(a0.y, b1.y, acc[0][1], 0, 0, 0);
            acc[1][0] = __builtin_amdgcn_mfma_f32_32x32x16_fp8_fp8(a1.y, b0.y, acc[1][0], 0, 0, 0);
            acc[1][1] = __builtin_amdgcn_mfma_f32_32x32x16_fp8_fp8(a1.y, b1.y, acc[1][1], 0, 0, 0);
        }
        __syncthreads();
    }

    // epilogue: 32x32 C/D: col = lane&31, row = (r&3)+8*(r>>2)+4*(lane>>5)
    float pn0 = 0.f, pn1 = 0.f;
    #pragma unroll
    for (int mt = 0; mt < 2; ++mt)
        #pragma unroll
        for (int rr = 0; rr < 16; ++rr) {
            int rowm = wm + mt * 32 + (rr & 3) + 8 * (rr >> 2) + 4 * khalf;
            int h = h0 + rowm;
            float tv = t1[b * H_ + h];
            float vv = v[h];
            pn0 += vv * tanh_fast(acc[mt][0][rr] * 0.015625f + tv);
            pn1 += vv * tanh_fast(acc[mt][1][rr] * 0.015625f + tv);
        }
    pn0 += __shfl_xor(pn0, 32);
    pn1 += __shfl_xor(pn1, 32);
    if (lane < 32) {
        atomicAdd(&logits[(size_t)b * S_ + s0 + wn + l32], pn0);
        atomicAdd(&logits[(size_t)b * S_ + s0 + wn + 32 + l32], pn1);
    }
}

// ---------------------------------------------------------------------------
// Fused softmax + context, fp32-exact from original enc.
// grid (64 s-chunks, B) = 2048 blocks (8/CU, ~32 waves/CU). Redundant
// softmax into LDS (trivial); each block accumulates its 16 s-rows over all
// 1024 h (coalesced float4, fully unrolled 16-deep ILP); atomicAdd into ctx.
// blockIdx.x==0 writes scores.
// ---------------------------------------------------------------------------
__global__ __launch_bounds__(256) void ctx_kernel(
    const float* __restrict__ enc, const float* __restrict__ logits,
    float* __restrict__ scores, float* __restrict__ ctx)
{
    __shared__ float sc[1024];
    __shared__ float red[8];
    const int b    = blockIdx.y;
    const int s0   = blockIdx.x * 16;
    const int tid  = threadIdx.x;
    const int lane = tid & 63;
    const int w    = tid >> 6;

    float4 lg = *reinterpret_cast<const float4*>(logits + (size_t)b * S_ + tid * 4);
    float mx = fmaxf(fmaxf(lg.x, lg.y), fmaxf(lg.z, lg.w));
    #pragma unroll
    for (int off = 1; off < 64; off <<= 1) mx = fmaxf(mx, __shfl_xor(mx, off));
    if (lane == 0) red[w] = mx;
    __syncthreads();
    mx = fmaxf(fmaxf(red[0], red[1]), fmaxf(red[2], red[3]));
    const float L2E = 1.44269504088896f;
    float e0 = __builtin_amdgcn_exp2f((lg.x - mx) * L2E);
    float e1 = __builtin_amdgcn_exp2f((lg.y - mx) * L2E);
    float e2 = __builtin_amdgcn_exp2f((lg.z - mx) * L2E);
    float e3 = __builtin_amdgcn_exp2f((lg.w - mx) * L2E);
    float s = e0 + e1 + e2 + e3;
    #pragma unroll
    for (int off = 1; off < 64; off <<= 1) s += __shfl_xor(s, off);
    if (lane == 0) red[4 + w] = s;
    __syncthreads();
    float inv = 1.f / (red[4] + red[5] + red[6] + red[7]);
    float4 sv = { e0 * inv, e1 * inv, e2 * inv, e3 * inv };
    *reinterpret_cast<float4*>(&sc[tid * 4]) = sv;
    if (blockIdx.x == 0)
        *reinterpret_cast<float4*>(scores + (size_t)b * S_ + tid * 4) = sv;
    __syncthreads();

    f32x4_t accv = {0.f, 0.f, 0.f, 0.f};
    const float* ebase = enc + ((size_t)b * S_ + s0) * H_ + tid * 4;
    #pragma unroll
    for (int si = 0; si < 16; ++si) {
        float wgt = sc[s0 + si];
        float4 ev = *reinterpret_cast<const float4*>(ebase + (size_t)si * H_);
        accv[0] += wgt * ev.x;
        accv[1] += wgt * ev.y;
        accv[2] += wgt * ev.z;
        accv[3] += wgt * ev.w;
    }
    float* cp = ctx + (size_t)b * H_ + tid * 4;
    atomicAdd(cp + 0, accv[0]);
    atomicAdd(cp + 1, accv[1]);
    atomicAdd(cp + 2, accv[2]);
    atomicAdd(cp + 3, accv[3]);
}

// ---------------------------------------------------------------------------
extern "C" void kernel_launch(void* const* d_in, const int* in_sizes, int n_in,
                              void* d_out, int out_size, void* d_ws, size_t ws_size,
                              hipStream_t stream)
{
    (void)in_sizes; (void)n_in; (void)out_size; (void)ws_size;
    const float* hidden = (const float*)d_in[0];
    const float* enc    = (const float*)d_in[1];
    const float* W      = (const float*)d_in[2];
    const float* bias   = (const float*)d_in[3];
    const float* v      = (const float*)d_in[4];

    float* out    = (float*)d_out;
    float* ctx    = out;             // [B,H]
    float* scores = out + B_ * H_;   // [B,S]

    float* logits = (float*)d_ws;                 // B*S f32   (128 KB)
    float* t1     = logits + B_ * S_;             // B*H f32   (128 KB)
    u8*    W2f8   = (u8*)(t1 + B_ * H_);          // 1 MB, kt-tiled
    u8*    encF8  = W2f8 + (size_t)H_ * H_;       // 32 MB, kt-tiled

    prep_kernel<<<dim3(1024 + 1024 + 256), 256, 0, stream>>>(
        enc, W, hidden, bias, encF8, W2f8, t1, logits, ctx);
    energy_kernel<<<dim3(2048), 256, 0, stream>>>(W2f8, encF8, t1, v, logits);
    ctx_kernel<<<dim3(S_ / 16, B_), 256, 0, stream>>>(enc, logits, scores, ctx);
}

// Round 9
// 315.250 us; speedup vs baseline: 1.0857x; 1.0857x over previous
//
#include <hip/hip_runtime.h>
#include <hip/hip_bf16.h>
#include <math.h>

#define B_ 32
#define H_ 1024
#define S_ 1024

typedef float  f32x4_t  __attribute__((ext_vector_type(4)));
typedef float  f32x16_t __attribute__((ext_vector_type(16)));
typedef long long i64;
typedef i64 i64x2 __attribute__((ext_vector_type(2)));
typedef unsigned char u8;

// async global->LDS, 16B per lane; LDS dest = wave-uniform base + lane*16.
__device__ __forceinline__ void gl_lds16(const void* g, void* l) {
    __builtin_amdgcn_global_load_lds(
        (const __attribute__((address_space(1))) unsigned int*)g,
        (__attribute__((address_space(3))) unsigned int*)l, 16, 0, 0);
}

// tanh via hw exp2 + rcp (~5 VALU inst, ~1e-6 abs err; saturates correctly)
__device__ __forceinline__ float tanh_fast(float x) {
    float e = __builtin_amdgcn_exp2f(x * 2.885390081777927f);  // e^(2x)
    return 1.f - 2.f * __builtin_amdgcn_rcpf(e + 1.f);
}

// fp8 k-permutation within a 32-k group: swap bits 3<->4 (involution).
__device__ __forceinline__ int kperm(int k) {
    return (k & ~24) | ((k & 8) << 1) | ((k & 16) >> 1);
}

// ---------------------------------------------------------------------------
// prep (one dispatch, 3 roles):
//  [0,4096):     encF8[b][kt][s][32B] = e4m3(enc[b][k][s]). Thread = (g,c,
//                4 s-values): only 8 strided float4 loads (32 VGPRs of data,
//                compiler keeps all 8 in flight), 4x 8B stores. 16 blocks/CU.
//  [4096,5120):  W2f8[kt][h][32B] = e4m3(64 * W[h][H+k]) + zero logits/ctx
//  [5120,5376):  t1[b,h] = bias[h] + sum_k hidden[b,k]*W[h,k]  (wave per h)
// ---------------------------------------------------------------------------
__global__ __launch_bounds__(256) void prep_kernel(
    const float* __restrict__ enc, const float* __restrict__ W,
    const float* __restrict__ hidden, const float* __restrict__ bias,
    u8* __restrict__ encF8, u8* __restrict__ W2f8,
    float* __restrict__ t1, float* __restrict__ logits,
    float* __restrict__ ctx)
{
    const int idx = blockIdx.x;
    const int tid = threadIdx.x;
    if (idx < 4096) {
        const int b  = idx >> 7;
        const int r  = idx & 127;
        const int kt = r >> 2;              // 0..31
        const int sb = (r & 3) * 256;       // s-base of this block
        const int s4 = tid >> 2;            // 0..63
        const int g  = (tid >> 1) & 1;      // low/high 8B of chunk
        const int c  = tid & 1;             // khalf plane
        const int s  = sb + s4 * 4;
        const int row0 = kt * 32 + g * 16 + c * 8;
        const float* ebase = enc + ((size_t)b * S_ + row0) * H_ + s;
        f32x4_t L0 = *reinterpret_cast<const f32x4_t*>(ebase);
        f32x4_t L1 = *reinterpret_cast<const f32x4_t*>(ebase + H_);
        f32x4_t L2 = *reinterpret_cast<const f32x4_t*>(ebase + 2 * H_);
        f32x4_t L3 = *reinterpret_cast<const f32x4_t*>(ebase + 3 * H_);
        f32x4_t L4 = *reinterpret_cast<const f32x4_t*>(ebase + 4 * H_);
        f32x4_t L5 = *reinterpret_cast<const f32x4_t*>(ebase + 5 * H_);
        f32x4_t L6 = *reinterpret_cast<const f32x4_t*>(ebase + 6 * H_);
        f32x4_t L7 = *reinterpret_cast<const f32x4_t*>(ebase + 7 * H_);
        u8* obase = encF8 + (size_t)b * 1048576 + (size_t)kt * 32768
                  + (size_t)s * 32 + c * 16 + g * 8;
        #pragma unroll
        for (int jj = 0; jj < 4; ++jj) {
            int w0 = __builtin_amdgcn_cvt_pk_fp8_f32(L0[jj], L1[jj], 0, false);
            w0     = __builtin_amdgcn_cvt_pk_fp8_f32(L2[jj], L3[jj], w0, true);
            int w1 = __builtin_amdgcn_cvt_pk_fp8_f32(L4[jj], L5[jj], 0, false);
            w1     = __builtin_amdgcn_cvt_pk_fp8_f32(L6[jj], L7[jj], w1, true);
            int2 payload = { w0, w1 };
            *reinterpret_cast<int2*>(obase + jj * 32) = payload;
        }
    } else if (idx < 5120) {
        int h = idx - 4096;  // one h row
        if (tid < 64) {      // zero logits (first 32768) then ctx (next 32768)
            int z = h * 64 + tid;
            if (z < B_ * S_) logits[z] = 0.f;
            else             ctx[z - B_ * S_] = 0.f;
        }
        int kt = tid >> 3;            // 0..31
        int q  = tid & 7;             // dest 4-byte word in 32B chunk
        int src = kperm(q * 4);       // contiguous 4 source floats
        float4 wv = *reinterpret_cast<const float4*>(
            W + (size_t)h * (2 * H_) + H_ + kt * 32 + src);
        int pw = __builtin_amdgcn_cvt_pk_fp8_f32(wv.x * 64.f, wv.y * 64.f, 0, false);
        pw     = __builtin_amdgcn_cvt_pk_fp8_f32(wv.z * 64.f, wv.w * 64.f, pw, true);
        *reinterpret_cast<int*>(W2f8 + (size_t)kt * 32768 + (size_t)h * 32 + q * 4) = pw;
    } else {
        int h    = (idx - 5120) * 4 + (tid >> 6);
        int lane = tid & 63;
        const float4* wp = reinterpret_cast<const float4*>(W + (size_t)h * (2 * H_));
        float4 w0 = wp[lane], w1 = wp[lane + 64], w2 = wp[lane + 128], w3 = wp[lane + 192];
        float bh = bias[h];
        for (int b = 0; b < B_; ++b) {
            const float4* hp = reinterpret_cast<const float4*>(hidden + b * H_);
            float4 h0 = hp[lane], h1 = hp[lane + 64], h2 = hp[lane + 128], h3 = hp[lane + 192];
            float a = w0.x*h0.x + w0.y*h0.y + w0.z*h0.z + w0.w*h0.w
                    + w1.x*h1.x + w1.y*h1.y + w1.z*h1.z + w1.w*h1.w
                    + w2.x*h2.x + w2.y*h2.y + w2.z*h2.z + w2.w*h2.w
                    + w3.x*h3.x + w3.y*h3.y + w3.z*h3.z + w3.w*h3.w;
            #pragma unroll
            for (int off = 1; off < 64; off <<= 1) a += __shfl_xor(a, off);
            if (lane == 0) t1[b * H_ + h] = a + bh;
        }
    }
}

// ---------------------------------------------------------------------------
// Energy GEMM (round-6 config verbatim, measured 78 µs / FETCH 21 MB /
// conflicts 0): fp8 e4m3, 128x128 tile, 32x32x16 MFMA (2x2/wave), BK=64
// barrier segments, double-buffered (32 KB LDS). XCD swizzle: all 8 h-tiles
// of one (s,b) group share id%8 -> same XCD -> B s-tile L2-resident.
//   D[h,s] = sum_k W2[h,k]*enc[b,k,s]; logits[b,s] += sum_h v[h]*tanh(D+t1)
// ---------------------------------------------------------------------------
__global__ __launch_bounds__(256) void energy_kernel(
    const u8* __restrict__ W2f8, const u8* __restrict__ encF8,
    const float* __restrict__ t1, const float* __restrict__ v,
    float* __restrict__ logits)
{
    __shared__ __align__(16) u8 As[2][2][4096];
    __shared__ __align__(16) u8 Bs[2][2][4096];

    const int id = blockIdx.x;
    const int q  = id >> 3, r = id & 7;
    const int ht = q & 7;
    const int g  = r + ((q >> 3) << 3);
    const int b  = g >> 3;
    const int h0 = ht * 128;
    const int s0 = (g & 7) * 128;

    const int tid   = threadIdx.x;
    const int lane  = tid & 63;
    const int wid   = tid >> 6;
    const int wm    = (wid & 1) * 64;
    const int wn    = (wid >> 1) * 64;
    const int l32   = lane & 31;
    const int khalf = lane >> 5;

    const int rowl = ((lane & 3) << 3) | ((lane >> 2) & 7);
    const int row  = (wid << 5) | rowl;
    const int cch  = lane >> 5;
    const size_t gofsA = (size_t)(h0 + row) * 32 + cch * 16;
    const size_t gofsB = (size_t)b * 1048576 + (size_t)(s0 + row) * 32 + cch * 16;

    gl_lds16(W2f8 + gofsA,          &As[0][0][tid * 16]);
    gl_lds16(W2f8 + gofsA + 32768,  &As[0][1][tid * 16]);
    gl_lds16(encF8 + gofsB,         &Bs[0][0][tid * 16]);
    gl_lds16(encF8 + gofsB + 32768, &Bs[0][1][tid * 16]);
    __syncthreads();

    f32x16_t acc[2][2] = {};
    const int sl  = ((((l32 & 7) << 2) | (l32 >> 3)) | (khalf << 5)) * 16;
    const int wAo = (wm >> 5) * 1024;
    const int wBo = (wn >> 5) * 1024;

    for (int seg = 0; seg < 16; ++seg) {
        const int cur = seg & 1, nxt = cur ^ 1;
        if (seg < 15) {
            const size_t o = (size_t)(2 * seg + 2) * 32768;
            gl_lds16(W2f8 + gofsA + o,          &As[nxt][0][tid * 16]);
            gl_lds16(W2f8 + gofsA + o + 32768,  &As[nxt][1][tid * 16]);
            gl_lds16(encF8 + gofsB + o,         &Bs[nxt][0][tid * 16]);
            gl_lds16(encF8 + gofsB + o + 32768, &Bs[nxt][1][tid * 16]);
        }
        #pragma unroll
        for (int t = 0; t < 2; ++t) {
            i64x2 a0 = *reinterpret_cast<const i64x2*>(&As[cur][t][wAo + sl]);
            i64x2 a1 = *reinterpret_cast<const i64x2*>(&As[cur][t][wAo + 1024 + sl]);
            i64x2 b0 = *reinterpret_cast<const i64x2*>(&Bs[cur][t][wBo + sl]);
            i64x2 b1 = *reinterpret_cast<const i64x2*>(&Bs[cur][t][wBo + 1024 + sl]);
            acc[0][0] = __builtin_amdgcn_mfma_f32_32x32x16_fp8_fp8(a0.x, b0.x, acc[0][0], 0, 0, 0);
            acc[0][1] = __builtin_amdgcn_mfma_f32_32x32x16_fp8_fp8(a0.x, b1.x, acc[0][1], 0, 0, 0);
            acc[1][0] = __builtin_amdgcn_mfma_f32_32x32x16_fp8_fp8(a1.x, b0.x, acc[1][0], 0, 0, 0);
            acc[1][1] = __builtin_amdgcn_mfma_f32_32x32x16_fp8_fp8(a1.x, b1.x, acc[1][1], 0, 0, 0);
            acc[0][0] = __builtin_amdgcn_mfma_f32_32x32x16_fp8_fp8(a0.y, b0.y, acc[0][0], 0, 0, 0);
            acc[0][1] = __builtin_amdgcn_mfma_f32_32x32x16_fp8_fp8(a0.y, b1.y, acc[0][1], 0, 0, 0);
            acc[1][0] = __builtin_amdgcn_mfma_f32_32x32x16_fp8_fp8(a1.y, b0.y, acc[1][0], 0, 0, 0);
            acc[1][1] = __builtin_amdgcn_mfma_f32_32x32x16_fp8_fp8(a1.y, b1.y, acc[1][1], 0, 0, 0);
        }
        __syncthreads();
    }

    // epilogue: 32x32 C/D: col = lane&31, row = (r&3)+8*(r>>2)+4*(lane>>5)
    float pn0 = 0.f, pn1 = 0.f;
    #pragma unroll
    for (int mt = 0; mt < 2; ++mt)
        #pragma unroll
        for (int rr = 0; rr < 16; ++rr) {
            int rowm = wm + mt * 32 + (rr & 3) + 8 * (rr >> 2) + 4 * khalf;
            int h = h0 + rowm;
            float tv = t1[b * H_ + h];
            float vv = v[h];
            pn0 += vv * tanh_fast(acc[mt][0][rr] * 0.015625f + tv);
            pn1 += vv * tanh_fast(acc[mt][1][rr] * 0.015625f + tv);
        }
    pn0 += __shfl_xor(pn0, 32);
    pn1 += __shfl_xor(pn1, 32);
    if (lane < 32) {
        atomicAdd(&logits[(size_t)b * S_ + s0 + wn + l32], pn0);
        atomicAdd(&logits[(size_t)b * S_ + s0 + wn + 32 + l32], pn1);
    }
}

// ---------------------------------------------------------------------------
// Fused softmax + context (round-6 config), fp32-exact from original enc.
// grid (16 s-chunks, B) = 512 blocks. Redundant softmax into LDS; each block
// accumulates its 64 s-rows over all 1024 h (coalesced float4); atomicAdd
// into ctx. blockIdx.x==0 writes scores.
// ---------------------------------------------------------------------------
__global__ __launch_bounds__(256) void ctx_kernel(
    const float* __restrict__ enc, const float* __restrict__ logits,
    float* __restrict__ scores, float* __restrict__ ctx)
{
    __shared__ float sc[1024];
    __shared__ float red[8];
    const int b    = blockIdx.y;
    const int s0   = blockIdx.x * 64;
    const int tid  = threadIdx.x;
    const int lane = tid & 63;
    const int w    = tid >> 6;

    float4 lg = *reinterpret_cast<const float4*>(logits + (size_t)b * S_ + tid * 4);
    float mx = fmaxf(fmaxf(lg.x, lg.y), fmaxf(lg.z, lg.w));
    #pragma unroll
    for (int off = 1; off < 64; off <<= 1) mx = fmaxf(mx, __shfl_xor(mx, off));
    if (lane == 0) red[w] = mx;
    __syncthreads();
    mx = fmaxf(fmaxf(red[0], red[1]), fmaxf(red[2], red[3]));
    const float L2E = 1.44269504088896f;
    float e0 = __builtin_amdgcn_exp2f((lg.x - mx) * L2E);
    float e1 = __builtin_amdgcn_exp2f((lg.y - mx) * L2E);
    float e2 = __builtin_amdgcn_exp2f((lg.z - mx) * L2E);
    float e3 = __builtin_amdgcn_exp2f((lg.w - mx) * L2E);
    float s = e0 + e1 + e2 + e3;
    #pragma unroll
    for (int off = 1; off < 64; off <<= 1) s += __shfl_xor(s, off);
    if (lane == 0) red[4 + w] = s;
    __syncthreads();
    float inv = 1.f / (red[4] + red[5] + red[6] + red[7]);
    float4 sv = { e0 * inv, e1 * inv, e2 * inv, e3 * inv };
    *reinterpret_cast<float4*>(&sc[tid * 4]) = sv;
    if (blockIdx.x == 0)
        *reinterpret_cast<float4*>(scores + (size_t)b * S_ + tid * 4) = sv;
    __syncthreads();

    f32x4_t accv = {0.f, 0.f, 0.f, 0.f};
    const float* ebase = enc + ((size_t)b * S_ + s0) * H_ + tid * 4;
    #pragma unroll 4
    for (int si = 0; si < 64; ++si) {
        float wgt = sc[s0 + si];
        float4 ev = *reinterpret_cast<const float4*>(ebase + (size_t)si * H_);
        accv[0] += wgt * ev.x;
        accv[1] += wgt * ev.y;
        accv[2] += wgt * ev.z;
        accv[3] += wgt * ev.w;
    }
    float* cp = ctx + (size_t)b * H_ + tid * 4;
    atomicAdd(cp + 0, accv[0]);
    atomicAdd(cp + 1, accv[1]);
    atomicAdd(cp + 2, accv[2]);
    atomicAdd(cp + 3, accv[3]);
}

// ---------------------------------------------------------------------------
extern "C" void kernel_launch(void* const* d_in, const int* in_sizes, int n_in,
                              void* d_out, int out_size, void* d_ws, size_t ws_size,
                              hipStream_t stream)
{
    (void)in_sizes; (void)n_in; (void)out_size; (void)ws_size;
    const float* hidden = (const float*)d_in[0];
    const float* enc    = (const float*)d_in[1];
    const float* W      = (const float*)d_in[2];
    const float* bias   = (const float*)d_in[3];
    const float* v      = (const float*)d_in[4];

    float* out    = (float*)d_out;
    float* ctx    = out;             // [B,H]
    float* scores = out + B_ * H_;   // [B,S]

    float* logits = (float*)d_ws;                 // B*S f32   (128 KB)
    float* t1     = logits + B_ * S_;             // B*H f32   (128 KB)
    u8*    W2f8   = (u8*)(t1 + B_ * H_);          // 1 MB, kt-tiled
    u8*    encF8  = W2f8 + (size_t)H_ * H_;       // 32 MB, kt-tiled

    prep_kernel<<<dim3(4096 + 1024 + 256), 256, 0, stream>>>(
        enc, W, hidden, bias, encF8, W2f8, t1, logits, ctx);
    energy_kernel<<<dim3(2048), 256, 0, stream>>>(W2f8, encF8, t1, v, logits);
    ctx_kernel<<<dim3(S_ / 64, B_), 256, 0, stream>>>(enc, logits, scores, ctx);
}

// Round 10
// 297.291 us; speedup vs baseline: 1.1513x; 1.0604x over previous
//
#include <hip/hip_runtime.h>
#include <hip/hip_bf16.h>
#include <math.h>

#define B_ 32
#define H_ 1024
#define S_ 1024

typedef float  f32x4_t  __attribute__((ext_vector_type(4)));
typedef float  f32x16_t __attribute__((ext_vector_type(16)));
typedef long long i64;
typedef i64 i64x2 __attribute__((ext_vector_type(2)));
typedef unsigned char u8;

// tanh via hw exp2 + rcp (~5 VALU inst, ~1e-6 abs err; saturates correctly)
__device__ __forceinline__ float tanh_fast(float x) {
    float e = __builtin_amdgcn_exp2f(x * 2.885390081777927f);  // e^(2x)
    return 1.f - 2.f * __builtin_amdgcn_rcpf(e + 1.f);
}

// fp8 k-permutation within a 32-k group: swap bits 3<->4 (involution).
__device__ __forceinline__ int kperm(int k) {
    return (k & ~24) | ((k & 8) << 1) | ((k & 16) >> 1);
}

// ---------------------------------------------------------------------------
// prep (round-9 version, verified improvement): one dispatch, 3 roles.
//  [0,4096):     encF8[b][kt][s][32B] = e4m3(enc[b][k][s]). Thread = (g,c,
//                4 s-values): 8 strided float4 loads held in flight, 4x 8B
//                stores. 16 blocks/CU.
//  [4096,5120):  W2f8[kt][h][32B] = e4m3(64 * W[h][H+k]) + zero logits/ctx
//  [5120,5376):  t1[b,h] = bias[h] + sum_k hidden[b,k]*W[h,k]  (wave per h)
// ---------------------------------------------------------------------------
__global__ __launch_bounds__(256) void prep_kernel(
    const float* __restrict__ enc, const float* __restrict__ W,
    const float* __restrict__ hidden, const float* __restrict__ bias,
    u8* __restrict__ encF8, u8* __restrict__ W2f8,
    float* __restrict__ t1, float* __restrict__ logits,
    float* __restrict__ ctx)
{
    const int idx = blockIdx.x;
    const int tid = threadIdx.x;
    if (idx < 4096) {
        const int b  = idx >> 7;
        const int r  = idx & 127;
        const int kt = r >> 2;              // 0..31
        const int sb = (r & 3) * 256;       // s-base of this block
        const int s4 = tid >> 2;            // 0..63
        const int g  = (tid >> 1) & 1;      // low/high 8B of chunk
        const int c  = tid & 1;             // khalf plane
        const int s  = sb + s4 * 4;
        const int row0 = kt * 32 + g * 16 + c * 8;
        const float* ebase = enc + ((size_t)b * S_ + row0) * H_ + s;
        f32x4_t L0 = *reinterpret_cast<const f32x4_t*>(ebase);
        f32x4_t L1 = *reinterpret_cast<const f32x4_t*>(ebase + H_);
        f32x4_t L2 = *reinterpret_cast<const f32x4_t*>(ebase + 2 * H_);
        f32x4_t L3 = *reinterpret_cast<const f32x4_t*>(ebase + 3 * H_);
        f32x4_t L4 = *reinterpret_cast<const f32x4_t*>(ebase + 4 * H_);
        f32x4_t L5 = *reinterpret_cast<const f32x4_t*>(ebase + 5 * H_);
        f32x4_t L6 = *reinterpret_cast<const f32x4_t*>(ebase + 6 * H_);
        f32x4_t L7 = *reinterpret_cast<const f32x4_t*>(ebase + 7 * H_);
        u8* obase = encF8 + (size_t)b * 1048576 + (size_t)kt * 32768
                  + (size_t)s * 32 + c * 16 + g * 8;
        #pragma unroll
        for (int jj = 0; jj < 4; ++jj) {
            int w0 = __builtin_amdgcn_cvt_pk_fp8_f32(L0[jj], L1[jj], 0, false);
            w0     = __builtin_amdgcn_cvt_pk_fp8_f32(L2[jj], L3[jj], w0, true);
            int w1 = __builtin_amdgcn_cvt_pk_fp8_f32(L4[jj], L5[jj], 0, false);
            w1     = __builtin_amdgcn_cvt_pk_fp8_f32(L6[jj], L7[jj], w1, true);
            int2 payload = { w0, w1 };
            *reinterpret_cast<int2*>(obase + jj * 32) = payload;
        }
    } else if (idx < 5120) {
        int h = idx - 4096;  // one h row
        if (tid < 64) {      // zero logits (first 32768) then ctx (next 32768)
            int z = h * 64 + tid;
            if (z < B_ * S_) logits[z] = 0.f;
            else             ctx[z - B_ * S_] = 0.f;
        }
        int kt = tid >> 3;            // 0..31
        int q  = tid & 7;             // dest 4-byte word in 32B chunk
        int src = kperm(q * 4);       // contiguous 4 source floats
        float4 wv = *reinterpret_cast<const float4*>(
            W + (size_t)h * (2 * H_) + H_ + kt * 32 + src);
        int pw = __builtin_amdgcn_cvt_pk_fp8_f32(wv.x * 64.f, wv.y * 64.f, 0, false);
        pw     = __builtin_amdgcn_cvt_pk_fp8_f32(wv.z * 64.f, wv.w * 64.f, pw, true);
        *reinterpret_cast<int*>(W2f8 + (size_t)kt * 32768 + (size_t)h * 32 + q * 4) = pw;
    } else {
        int h    = (idx - 5120) * 4 + (tid >> 6);
        int lane = tid & 63;
        const float4* wp = reinterpret_cast<const float4*>(W + (size_t)h * (2 * H_));
        float4 w0 = wp[lane], w1 = wp[lane + 64], w2 = wp[lane + 128], w3 = wp[lane + 192];
        float bh = bias[h];
        for (int b = 0; b < B_; ++b) {
            const float4* hp = reinterpret_cast<const float4*>(hidden + b * H_);
            float4 h0 = hp[lane], h1 = hp[lane + 64], h2 = hp[lane + 128], h3 = hp[lane + 192];
            float a = w0.x*h0.x + w0.y*h0.y + w0.z*h0.z + w0.w*h0.w
                    + w1.x*h1.x + w1.y*h1.y + w1.z*h1.z + w1.w*h1.w
                    + w2.x*h2.x + w2.y*h2.y + w2.z*h2.z + w2.w*h2.w
                    + w3.x*h3.x + w3.y*h3.y + w3.z*h3.z + w3.w*h3.w;
            #pragma unroll
            for (int off = 1; off < 64; off <<= 1) a += __shfl_xor(a, off);
            if (lane == 0) t1[b * H_ + h] = a + bh;
        }
    }
}

// ---------------------------------------------------------------------------
// Energy GEMM v8 — FLAT (no LDS, no barriers): fragments loaded straight
// global->VGPR. The kt-tiled layouts make a wave's fragment load a fully
// coalesced 1KB segment (64 lanes x 16B at (row)*32 + khalf*16). W2f8 (1MB)
// + XCD-pinned B s-tiles are L2-resident (round-6 verified, FETCH 21MB).
// Depth-1 register prefetch: load kt+1 while computing kt; no syncthreads
// anywhere -> compiler uses fine-grained vmcnt (AITER-style), all waves
// pipeline independently.
//   D[h,s] = sum_k W2[h,k]*enc[b,k,s]; logits[b,s] += sum_h v[h]*tanh(D+t1)
// ---------------------------------------------------------------------------
__global__ __launch_bounds__(256) void energy_kernel(
    const u8* __restrict__ W2f8, const u8* __restrict__ encF8,
    const float* __restrict__ t1, const float* __restrict__ v,
    float* __restrict__ logits)
{
    // XCD decode (round-6): all 8 h-tiles of one (s,b) group share id%8.
    const int id = blockIdx.x;
    const int q  = id >> 3, r = id & 7;
    const int ht = q & 7;
    const int g  = r + ((q >> 3) << 3);
    const int b  = g >> 3;
    const int h0 = ht * 128;
    const int s0 = (g & 7) * 128;

    const int tid   = threadIdx.x;
    const int lane  = tid & 63;
    const int wid   = tid >> 6;
    const int wm    = (wid & 1) * 64;
    const int wn    = (wid >> 1) * 64;
    const int l32   = lane & 31;
    const int khalf = lane >> 5;

    // per-lane fragment stream bases (advance 32768 B per kt)
    const u8* aP = W2f8 + (size_t)(h0 + wm + l32) * 32 + khalf * 16;
    const u8* bP = encF8 + (size_t)b * 1048576
                 + (size_t)(s0 + wn + l32) * 32 + khalf * 16;

    f32x16_t acc[2][2] = {};

    i64x2 ca0 = *reinterpret_cast<const i64x2*>(aP);
    i64x2 ca1 = *reinterpret_cast<const i64x2*>(aP + 1024);
    i64x2 cb0 = *reinterpret_cast<const i64x2*>(bP);
    i64x2 cb1 = *reinterpret_cast<const i64x2*>(bP + 1024);
    const u8* aN = aP + 32768;
    const u8* bN = bP + 32768;

    for (int kt = 0; kt < 31; ++kt) {
        i64x2 na0 = *reinterpret_cast<const i64x2*>(aN);
        i64x2 na1 = *reinterpret_cast<const i64x2*>(aN + 1024);
        i64x2 nb0 = *reinterpret_cast<const i64x2*>(bN);
        i64x2 nb1 = *reinterpret_cast<const i64x2*>(bN + 1024);
        aN += 32768; bN += 32768;

        acc[0][0] = __builtin_amdgcn_mfma_f32_32x32x16_fp8_fp8(ca0.x, cb0.x, acc[0][0], 0, 0, 0);
        acc[0][1] = __builtin_amdgcn_mfma_f32_32x32x16_fp8_fp8(ca0.x, cb1.x, acc[0][1], 0, 0, 0);
        acc[1][0] = __builtin_amdgcn_mfma_f32_32x32x16_fp8_fp8(ca1.x, cb0.x, acc[1][0], 0, 0, 0);
        acc[1][1] = __builtin_amdgcn_mfma_f32_32x32x16_fp8_fp8(ca1.x, cb1.x, acc[1][1], 0, 0, 0);
        acc[0][0] = __builtin_amdgcn_mfma_f32_32x32x16_fp8_fp8(ca0.y, cb0.y, acc[0][0], 0, 0, 0);
        acc[0][1] = __builtin_amdgcn_mfma_f32_32x32x16_fp8_fp8(ca0.y, cb1.y, acc[0][1], 0, 0, 0);
        acc[1][0] = __builtin_amdgcn_mfma_f32_32x32x16_fp8_fp8(ca1.y, cb0.y, acc[1][0], 0, 0, 0);
        acc[1][1] = __builtin_amdgcn_mfma_f32_32x32x16_fp8_fp8(ca1.y, cb1.y, acc[1][1], 0, 0, 0);

        ca0 = na0; ca1 = na1; cb0 = nb0; cb1 = nb1;
    }
    acc[0][0] = __builtin_amdgcn_mfma_f32_32x32x16_fp8_fp8(ca0.x, cb0.x, acc[0][0], 0, 0, 0);
    acc[0][1] = __builtin_amdgcn_mfma_f32_32x32x16_fp8_fp8(ca0.x, cb1.x, acc[0][1], 0, 0, 0);
    acc[1][0] = __builtin_amdgcn_mfma_f32_32x32x16_fp8_fp8(ca1.x, cb0.x, acc[1][0], 0, 0, 0);
    acc[1][1] = __builtin_amdgcn_mfma_f32_32x32x16_fp8_fp8(ca1.x, cb1.x, acc[1][1], 0, 0, 0);
    acc[0][0] = __builtin_amdgcn_mfma_f32_32x32x16_fp8_fp8(ca0.y, cb0.y, acc[0][0], 0, 0, 0);
    acc[0][1] = __builtin_amdgcn_mfma_f32_32x32x16_fp8_fp8(ca0.y, cb1.y, acc[0][1], 0, 0, 0);
    acc[1][0] = __builtin_amdgcn_mfma_f32_32x32x16_fp8_fp8(ca1.y, cb0.y, acc[1][0], 0, 0, 0);
    acc[1][1] = __builtin_amdgcn_mfma_f32_32x32x16_fp8_fp8(ca1.y, cb1.y, acc[1][1], 0, 0, 0);

    // epilogue: 32x32 C/D: col = lane&31, row = (r&3)+8*(r>>2)+4*(lane>>5)
    float pn0 = 0.f, pn1 = 0.f;
    #pragma unroll
    for (int mt = 0; mt < 2; ++mt)
        #pragma unroll
        for (int rr = 0; rr < 16; ++rr) {
            int rowm = wm + mt * 32 + (rr & 3) + 8 * (rr >> 2) + 4 * khalf;
            int h = h0 + rowm;
            float tv = t1[b * H_ + h];
            float vv = v[h];
            pn0 += vv * tanh_fast(acc[mt][0][rr] * 0.015625f + tv);
            pn1 += vv * tanh_fast(acc[mt][1][rr] * 0.015625f + tv);
        }
    pn0 += __shfl_xor(pn0, 32);
    pn1 += __shfl_xor(pn1, 32);
    if (lane < 32) {
        atomicAdd(&logits[(size_t)b * S_ + s0 + wn + l32], pn0);
        atomicAdd(&logits[(size_t)b * S_ + s0 + wn + 32 + l32], pn1);
    }
}

// ---------------------------------------------------------------------------
// Fused softmax + context (round-6 config), fp32-exact from original enc.
// grid (16 s-chunks, B) = 512 blocks. Redundant softmax into LDS; each block
// accumulates its 64 s-rows over all 1024 h (coalesced float4); atomicAdd
// into ctx. blockIdx.x==0 writes scores.
// ---------------------------------------------------------------------------
__global__ __launch_bounds__(256) void ctx_kernel(
    const float* __restrict__ enc, const float* __restrict__ logits,
    float* __restrict__ scores, float* __restrict__ ctx)
{
    __shared__ float sc[1024];
    __shared__ float red[8];
    const int b    = blockIdx.y;
    const int s0   = blockIdx.x * 64;
    const int tid  = threadIdx.x;
    const int lane = tid & 63;
    const int w    = tid >> 6;

    float4 lg = *reinterpret_cast<const float4*>(logits + (size_t)b * S_ + tid * 4);
    float mx = fmaxf(fmaxf(lg.x, lg.y), fmaxf(lg.z, lg.w));
    #pragma unroll
    for (int off = 1; off < 64; off <<= 1) mx = fmaxf(mx, __shfl_xor(mx, off));
    if (lane == 0) red[w] = mx;
    __syncthreads();
    mx = fmaxf(fmaxf(red[0], red[1]), fmaxf(red[2], red[3]));
    const float L2E = 1.44269504088896f;
    float e0 = __builtin_amdgcn_exp2f((lg.x - mx) * L2E);
    float e1 = __builtin_amdgcn_exp2f((lg.y - mx) * L2E);
    float e2 = __builtin_amdgcn_exp2f((lg.z - mx) * L2E);
    float e3 = __builtin_amdgcn_exp2f((lg.w - mx) * L2E);
    float s = e0 + e1 + e2 + e3;
    #pragma unroll
    for (int off = 1; off < 64; off <<= 1) s += __shfl_xor(s, off);
    if (lane == 0) red[4 + w] = s;
    __syncthreads();
    float inv = 1.f / (red[4] + red[5] + red[6] + red[7]);
    float4 sv = { e0 * inv, e1 * inv, e2 * inv, e3 * inv };
    *reinterpret_cast<float4*>(&sc[tid * 4]) = sv;
    if (blockIdx.x == 0)
        *reinterpret_cast<float4*>(scores + (size_t)b * S_ + tid * 4) = sv;
    __syncthreads();

    f32x4_t accv = {0.f, 0.f, 0.f, 0.f};
    const float* ebase = enc + ((size_t)b * S_ + s0) * H_ + tid * 4;
    #pragma unroll 4
    for (int si = 0; si < 64; ++si) {
        float wgt = sc[s0 + si];
        float4 ev = *reinterpret_cast<const float4*>(ebase + (size_t)si * H_);
        accv[0] += wgt * ev.x;
        accv[1] += wgt * ev.y;
        accv[2] += wgt * ev.z;
        accv[3] += wgt * ev.w;
    }
    float* cp = ctx + (size_t)b * H_ + tid * 4;
    atomicAdd(cp + 0, accv[0]);
    atomicAdd(cp + 1, accv[1]);
    atomicAdd(cp + 2, accv[2]);
    atomicAdd(cp + 3, accv[3]);
}

// ---------------------------------------------------------------------------
extern "C" void kernel_launch(void* const* d_in, const int* in_sizes, int n_in,
                              void* d_out, int out_size, void* d_ws, size_t ws_size,
                              hipStream_t stream)
{
    (void)in_sizes; (void)n_in; (void)out_size; (void)ws_size;
    const float* hidden = (const float*)d_in[0];
    const float* enc    = (const float*)d_in[1];
    const float* W      = (const float*)d_in[2];
    const float* bias   = (const float*)d_in[3];
    const float* v      = (const float*)d_in[4];

    float* out    = (float*)d_out;
    float* ctx    = out;             // [B,H]
    float* scores = out + B_ * H_;   // [B,S]

    float* logits = (float*)d_ws;                 // B*S f32   (128 KB)
    float* t1     = logits + B_ * S_;             // B*H f32   (128 KB)
    u8*    W2f8   = (u8*)(t1 + B_ * H_);          // 1 MB, kt-tiled
    u8*    encF8  = W2f8 + (size_t)H_ * H_;       // 32 MB, kt-tiled

    prep_kernel<<<dim3(4096 + 1024 + 256), 256, 0, stream>>>(
        enc, W, hidden, bias, encF8, W2f8, t1, logits, ctx);
    energy_kernel<<<dim3(2048), 256, 0, stream>>>(W2f8, encF8, t1, v, logits);
    ctx_kernel<<<dim3(S_ / 64, B_), 256, 0, stream>>>(enc, logits, scores, ctx);
}